// Round 6
// baseline (572.291 us; speedup 1.0000x reference)
//
#include <hip/hip_runtime.h>

#define BN_EPS 1e-5f

typedef __attribute__((ext_vector_type(8))) short short8;
typedef __attribute__((ext_vector_type(8))) unsigned short ushort8v;
typedef __attribute__((ext_vector_type(4))) float floatx4;

#define GLL(gp, lp)                                                            \
    __builtin_amdgcn_global_load_lds(                                          \
        (const __attribute__((address_space(1))) void*)(gp),                   \
        (__attribute__((address_space(3))) void*)(lp), 16, 0, 0)

__device__ inline unsigned short f2bf(float f) {
    unsigned int u = __float_as_uint(f);
    unsigned int r = (u + 0x7FFF + ((u >> 16) & 1)) >> 16;  // RNE
    return (unsigned short)r;
}

__device__ inline float bf2f(unsigned short u) {
    return __uint_as_float(((unsigned int)u) << 16);
}

// ---------------- prep: count in-degree + fp32->bf16 casts (merged) --------

__global__ void prep_kernel(const int* __restrict__ col, int* __restrict__ cnt,
                            const float* __restrict__ x, const float* __restrict__ W1,
                            const float* __restrict__ W2, ushort* __restrict__ xbf,
                            ushort* __restrict__ W1bf, ushort* __restrict__ W2bf,
                            int E, int n4x, int n4w) {
    int i = blockIdx.x * blockDim.x + threadIdx.x;
    if (i < E) {
        atomicAdd(&cnt[col[i]], 1);
        return;
    }
    int j = i - E;
    const float* src;
    ushort* dst;
    if (j < n4x) { src = x; dst = xbf; }
    else if (j < n4x + n4w) { src = W1; dst = W1bf; j -= n4x; }
    else if (j < n4x + 2 * n4w) { src = W2; dst = W2bf; j -= n4x + n4w; }
    else return;
    float4 v = ((const float4*)src)[j];
    ushort4 o;
    o.x = f2bf(v.x); o.y = f2bf(v.y); o.z = f2bf(v.z); o.w = f2bf(v.w);
    ((ushort4*)dst)[j] = o;
}

// single-block scan over N counts -> rowptr/cursor; also computes dis.
__global__ __launch_bounds__(1024) void scan_dis_kernel(
    const int* __restrict__ cnt, float* __restrict__ dis,
    int* __restrict__ rowptr, int* __restrict__ cursor, int N) {
    __shared__ int sums[1024];
    int t = threadIdx.x;
    int per = (N + 1023) / 1024;
    int start = t * per;
    int local = 0;
    for (int i = 0; i < per; i++) {
        int idx = start + i;
        if (idx < N) {
            int cv = cnt[idx];
            local += cv;
            dis[idx] = rsqrtf((float)(cv + 1));   // +1 self loop
        }
    }
    sums[t] = local;
    __syncthreads();
    for (int off = 1; off < 1024; off <<= 1) {
        int v = (t >= off) ? sums[t - off] : 0;
        __syncthreads();
        sums[t] += v;
        __syncthreads();
    }
    int run = (t == 0) ? 0 : sums[t - 1];
    for (int i = 0; i < per; i++) {
        int idx = start + i;
        if (idx < N) {
            rowptr[idx] = run;
            cursor[idx] = run;
            run += cnt[idx];
        }
    }
    if (t == 0) rowptr[N] = sums[1023];
}

// scatter: build CSR adjacency with pre-baked dis[row].
__global__ void scatter_kernel(const int* __restrict__ row, const int* __restrict__ col,
                               const float* __restrict__ dis,
                               int* __restrict__ cursor, int2* __restrict__ adjw, int E) {
    int e = blockIdx.x * blockDim.x + threadIdx.x;
    if (e < E) {
        int r = row[e];
        int pos = atomicAdd(&cursor[col[e]], 1);
        adjw[pos] = make_int2(r, __float_as_int(dis[r]));
    }
}

// ---------------- last-block BN finalize (shared helper) -------------------
// After a grid writes per-chunk partials psum/psumsq [C][chunks], the LAST
// block (device-scope ticket) reduces them -> scale/shift. Coalesced:
// wave-per-channel, lanes over chunks (proven bn_reduce shape).

__device__ inline void bn_lastblock_reduce(
    const float* __restrict__ psum, const float* __restrict__ psumsq,
    const float* __restrict__ gamma, const float* __restrict__ beta,
    float* __restrict__ scale, float* __restrict__ shift,
    int C, int chunks, int Mrows) {
    int wave = threadIdx.x >> 6;
    int lane = threadIdx.x & 63;
    float invM = 1.0f / (float)Mrows;
    for (int c = wave; c < C; c += 4) {
        float s = 0.f, q = 0.f;
        for (int k = lane; k < chunks; k += 64) {
            s += psum[(size_t)c * chunks + k];
            q += psumsq[(size_t)c * chunks + k];
        }
#pragma unroll
        for (int off = 32; off > 0; off >>= 1) {
            s += __shfl_down(s, off, 64);
            q += __shfl_down(q, off, 64);
        }
        if (lane == 0) {
            float mean = s * invM;
            float var = q * invM - mean * mean;
            float sc = gamma[c] * rsqrtf(var + BN_EPS);
            scale[c] = sc;
            shift[c] = beta[c] - mean * sc;
        }
    }
}

// ---------------- bf16 gather, C=256 channels, one BLOCK per node ----------
// R3-PROVEN structure — do not restructure (R4/R5 lessons: wave-per-node and
// coop grid-stride variants were 4-10x slower). 4 waves x 64 lanes x ushort4,
// named scalar accumulators, 2-way edge unroll, LDS reduce.

__global__ __launch_bounds__(256) void gather_bf_kernel(
    const ushort* __restrict__ xl, const int* __restrict__ rowptr,
    const int2* __restrict__ adjw, const float* __restrict__ dis,
    ushort* __restrict__ h) {
    int v = blockIdx.x;
    int wave = threadIdx.x >> 6;
    int lane = threadIdx.x & 63;
    float dv = dis[v];

    float a0 = 0.f, a1 = 0.f, a2 = 0.f, a3 = 0.f;
    float b0 = 0.f, b1 = 0.f, b2 = 0.f, b3 = 0.f;
    int e0 = rowptr[v], e1 = rowptr[v + 1];
    int e = e0 + wave;
    for (; e + 4 < e1; e += 8) {
        int2 ea = adjw[e];
        int2 eb = adjw[e + 4];
        float wa = __int_as_float(ea.y) * dv;
        float wb = __int_as_float(eb.y) * dv;
        ushort4 ua = ((const ushort4*)xl)[(size_t)ea.x * 64 + lane];
        ushort4 ub = ((const ushort4*)xl)[(size_t)eb.x * 64 + lane];
        a0 = fmaf(bf2f(ua.x), wa, a0);
        a1 = fmaf(bf2f(ua.y), wa, a1);
        a2 = fmaf(bf2f(ua.z), wa, a2);
        a3 = fmaf(bf2f(ua.w), wa, a3);
        b0 = fmaf(bf2f(ub.x), wb, b0);
        b1 = fmaf(bf2f(ub.y), wb, b1);
        b2 = fmaf(bf2f(ub.z), wb, b2);
        b3 = fmaf(bf2f(ub.w), wb, b3);
    }
    if (e < e1) {
        int2 ea = adjw[e];
        float wa = __int_as_float(ea.y) * dv;
        ushort4 ua = ((const ushort4*)xl)[(size_t)ea.x * 64 + lane];
        a0 = fmaf(bf2f(ua.x), wa, a0);
        a1 = fmaf(bf2f(ua.y), wa, a1);
        a2 = fmaf(bf2f(ua.z), wa, a2);
        a3 = fmaf(bf2f(ua.w), wa, a3);
    }
    a0 += b0; a1 += b1; a2 += b2; a3 += b3;

    __shared__ float4 red[4][64];
    red[wave][lane] = make_float4(a0, a1, a2, a3);
    __syncthreads();
    if (wave == 0) {
        float4 s = red[0][lane];
        float4 b = red[1][lane];
        float4 c = red[2][lane];
        float4 d = red[3][lane];
        s.x += b.x + c.x + d.x;
        s.y += b.y + c.y + d.y;
        s.z += b.z + c.z + d.z;
        s.w += b.w + c.w + d.w;
        ushort4 u = ((const ushort4*)xl)[(size_t)v * 64 + lane];
        float w2 = dv * dv;
        s.x = fmaf(bf2f(u.x), w2, s.x);
        s.y = fmaf(bf2f(u.y), w2, s.y);
        s.z = fmaf(bf2f(u.z), w2, s.z);
        s.w = fmaf(bf2f(u.w), w2, s.w);
        ushort4 o;
        o.x = f2bf(s.x); o.y = f2bf(s.y); o.z = f2bf(s.z); o.w = f2bf(s.w);
        ((ushort4*)h)[(size_t)v * 64 + lane] = o;
    }
}

// ---------------- MFMA GEMM: C[M,N] = A[M,K] @ B[N,K]^T (bf16 in/out) ------
// STATS: epilogue emits per-column partial sum/sumsq into psum[col][chunk];
//        the LAST block (ticket) reduces them -> scaleOut/shiftOut in-kernel
//        (replaces the bn_reduce1 dispatch).
// BN_A:  A-tile is reg-staged global->reg, BN(scale,shift from global)+ReLU
//        applied, then ds_write to LDS (R3-proven direct-read form).

template <bool STATS, bool BN_A>
__global__ __launch_bounds__(256) void gemm_mfma_kernel(
    const ushort* __restrict__ A, const ushort* __restrict__ B,
    ushort* __restrict__ Cout, float* __restrict__ psum, float* __restrict__ psumsq,
    const float* __restrict__ bnScale, const float* __restrict__ bnShift,
    const float* __restrict__ gammaS, const float* __restrict__ betaS,
    float* __restrict__ scaleOut, float* __restrict__ shiftOut,
    int* __restrict__ ticket,
    int chunks, int M, int N, int K) {
    __shared__ ushort As[128 * 32];
    __shared__ ushort Bs[128 * 32];
    int tid = threadIdx.x;
    int wave = tid >> 6;
    int lane = tid & 63;
    int quad = lane >> 4;
    int l15 = lane & 15;
    int m0 = blockIdx.y * 128;
    int n0 = blockIdx.x * 128;

    int srow = lane >> 2;
    int skoff = (lane & 3) * 8;

    floatx4 acc[4][4];
#pragma unroll
    for (int i = 0; i < 4; i++)
#pragma unroll
        for (int j = 0; j < 4; j++) acc[i][j] = (floatx4){0.f, 0.f, 0.f, 0.f};

    int wm = (wave & 1) * 64;
    int wn = (wave >> 1) * 64;

    for (int k0 = 0; k0 < K; k0 += 32) {
#pragma unroll
        for (int cc = 0; cc < 2; cc++) {
            int c = wave * 2 + cc;
            int brow = n0 + c * 16 + srow;
            const ushort* gb = B + (size_t)brow * K + k0 + skoff;
            GLL(gb, (char*)Bs + c * 1024);
            if (!BN_A) {
                int arow = min(m0 + c * 16 + srow, M - 1);
                const ushort* ga = A + (size_t)arow * K + k0 + skoff;
                GLL(ga, (char*)As + c * 1024);
            }
        }
        if (BN_A) {
            const float* scp = bnScale + k0 + skoff;
            const float* shp = bnShift + k0 + skoff;
            float4 sa = *(const float4*)scp;
            float4 sb = *(const float4*)(scp + 4);
            float4 ha = *(const float4*)shp;
            float4 hb = *(const float4*)(shp + 4);
            float scv[8] = {sa.x, sa.y, sa.z, sa.w, sb.x, sb.y, sb.z, sb.w};
            float shv[8] = {ha.x, ha.y, ha.z, ha.w, hb.x, hb.y, hb.z, hb.w};
#pragma unroll
            for (int cc = 0; cc < 2; cc++) {
                int c = wave * 2 + cc;
                int arow = min(m0 + c * 16 + srow, M - 1);
                ushort8v araw = *(const ushort8v*)(A + (size_t)arow * K + k0 + skoff);
                ushort8v t;
#pragma unroll
                for (int j = 0; j < 8; j++) {
                    float f = fmaxf(fmaf(bf2f(araw[j]), scv[j], shv[j]), 0.f);
                    t[j] = f2bf(f);
                }
                // tail barrier of previous iter guarantees buffer is free
                *(ushort8v*)((char*)As + c * 1024 + (size_t)lane * 16) = t;
            }
        }
        __syncthreads();

        short8 af[4], bfr[4];
#pragma unroll
        for (int i = 0; i < 4; i++) {
            int r = wm + i * 16 + l15;
            af[i] = *(const short8*)(As + r * 32 + quad * 8);
        }
#pragma unroll
        for (int j = 0; j < 4; j++) {
            int r = wn + j * 16 + l15;
            bfr[j] = *(const short8*)(Bs + r * 32 + quad * 8);
        }
#pragma unroll
        for (int i = 0; i < 4; i++)
#pragma unroll
            for (int j = 0; j < 4; j++)
                acc[i][j] = __builtin_amdgcn_mfma_f32_16x16x32_bf16(af[i], bfr[j], acc[i][j], 0, 0, 0);
        __syncthreads();
    }

#pragma unroll
    for (int i = 0; i < 4; i++) {
#pragma unroll
        for (int r = 0; r < 4; r++) {
            int row = m0 + wm + i * 16 + quad * 4 + r;
            if (row < M) {
                ushort* cp = Cout + (size_t)row * N + n0 + wn + l15;
#pragma unroll
                for (int j = 0; j < 4; j++) cp[j * 16] = f2bf(acc[i][j][r]);
            }
        }
    }

    if (STATS) {
        float s[4] = {0.f, 0.f, 0.f, 0.f};
        float q[4] = {0.f, 0.f, 0.f, 0.f};
#pragma unroll
        for (int i = 0; i < 4; i++) {
#pragma unroll
            for (int r = 0; r < 4; r++) {
                if (m0 + wm + i * 16 + quad * 4 + r < M) {
#pragma unroll
                    for (int j = 0; j < 4; j++) {
                        float v = acc[i][j][r];
                        s[j] += v;
                        q[j] += v * v;
                    }
                }
            }
        }
#pragma unroll
        for (int j = 0; j < 4; j++) {
            s[j] += __shfl_xor(s[j], 16, 64);
            s[j] += __shfl_xor(s[j], 32, 64);
            q[j] += __shfl_xor(q[j], 16, 64);
            q[j] += __shfl_xor(q[j], 32, 64);
        }
        __shared__ float sArr[4][64];
        __shared__ float qArr[4][64];
        if (quad == 0) {
#pragma unroll
            for (int j = 0; j < 4; j++) {
                sArr[wave][j * 16 + l15] = s[j];
                qArr[wave][j * 16 + l15] = q[j];
            }
        }
        __syncthreads();
        if (tid < 128) {
            int half = tid >> 6;
            int cc = tid & 63;
            float ss = sArr[half * 2][cc] + sArr[half * 2 + 1][cc];
            float qq = qArr[half * 2][cc] + qArr[half * 2 + 1][cc];
            int colI = n0 + half * 64 + cc;
            psum[(size_t)colI * chunks + blockIdx.y] = ss;
            psumsq[(size_t)colI * chunks + blockIdx.y] = qq;
        }

        // ---- last-block BN1 finalize (replaces bn_reduce1 dispatch) ----
        __shared__ int lastFlag;
        __threadfence();                       // device-scope: publish partials
        __syncthreads();
        if (tid == 0) {
            int nblk = gridDim.x * gridDim.y;
            int t = atomicAdd(ticket, 1);
            lastFlag = (t == nblk - 1);
        }
        __syncthreads();
        if (lastFlag) {
            __threadfence();                   // acquire side
            bn_lastblock_reduce(psum, psumsq, gammaS, betaS, scaleOut, shiftOut,
                                N, chunks, M);
        }
    }
}

// ---------------- BN2 partial stats on bf16 h (channel-major [C][chunks]) ---
// Non-atomic chunk-owned partials; LAST block reduces -> scale2/shift2
// (replaces the bn_reduce2 dispatch).

__global__ __launch_bounds__(256) void bn_partial_kernel(
    const ushort* __restrict__ h, float* __restrict__ psum, float* __restrict__ psumsq,
    const float* __restrict__ gamma, const float* __restrict__ beta,
    float* __restrict__ scale, float* __restrict__ shift,
    int* __restrict__ ticket,
    int N, int IC, int rows_per_chunk, int chunks) {
    int groups = IC >> 2;          // 64 for C=256
    int rpi = 256 / groups;        // 4
    int t = threadIdx.x;
    int g = t & (groups - 1);
    int ro = t / groups;
    int r0 = blockIdx.x * rows_per_chunk;
    int r1 = min(r0 + rows_per_chunk, N);

    float4 s = make_float4(0.f, 0.f, 0.f, 0.f);
    float4 q = make_float4(0.f, 0.f, 0.f, 0.f);
    for (int r = r0 + ro; r < r1; r += rpi) {
        ushort4 u = *(const ushort4*)(h + (size_t)r * IC + g * 4);
        float vx = bf2f(u.x), vy = bf2f(u.y), vz = bf2f(u.z), vw = bf2f(u.w);
        s.x += vx; s.y += vy; s.z += vz; s.w += vw;
        q.x += vx * vx; q.y += vy * vy; q.z += vz * vz; q.w += vw * vw;
    }

    __shared__ float4 redS[256];
    __shared__ float4 redQ[256];
    redS[t] = s;
    redQ[t] = q;
    __syncthreads();
    if (ro == 0) {
        for (int i = 1; i < rpi; i++) {
            float4 o = redS[t + i * groups];
            s.x += o.x; s.y += o.y; s.z += o.z; s.w += o.w;
            float4 p = redQ[t + i * groups];
            q.x += p.x; q.y += p.y; q.z += p.z; q.w += p.w;
        }
        int k = blockIdx.x;
        psum[(size_t)(4 * g + 0) * chunks + k] = s.x;
        psum[(size_t)(4 * g + 1) * chunks + k] = s.y;
        psum[(size_t)(4 * g + 2) * chunks + k] = s.z;
        psum[(size_t)(4 * g + 3) * chunks + k] = s.w;
        psumsq[(size_t)(4 * g + 0) * chunks + k] = q.x;
        psumsq[(size_t)(4 * g + 1) * chunks + k] = q.y;
        psumsq[(size_t)(4 * g + 2) * chunks + k] = q.z;
        psumsq[(size_t)(4 * g + 3) * chunks + k] = q.w;
    }

    // ---- last-block BN2 finalize ----
    __shared__ int lastFlag;
    __threadfence();
    __syncthreads();
    if (t == 0) {
        int tk = atomicAdd(ticket, 1);
        lastFlag = (tk == (int)gridDim.x - 1);
    }
    __syncthreads();
    if (lastFlag) {
        __threadfence();
        bn_lastblock_reduce(psum, psumsq, gamma, beta, scale, shift, IC, chunks, N);
    }
}

// ---------------- final: out = relu(bn2(h2) + x), large grid (bf16 h2) ------

__global__ void final_kernel(const ushort* __restrict__ h2, const float* __restrict__ x,
                             const float* __restrict__ scale, const float* __restrict__ shift,
                             float* __restrict__ out, int total4, int C4) {
    int idx = blockIdx.x * blockDim.x + threadIdx.x;
    if (idx >= total4) return;
    int c4 = (idx & (C4 - 1)) * 4;
    ushort4 u = ((const ushort4*)h2)[idx];
    float4 xv = ((const float4*)x)[idx];
    float4 o;
    o.x = fmaxf(fmaf(bf2f(u.x), scale[c4 + 0], shift[c4 + 0]) + xv.x, 0.f);
    o.y = fmaxf(fmaf(bf2f(u.y), scale[c4 + 1], shift[c4 + 1]) + xv.y, 0.f);
    o.z = fmaxf(fmaf(bf2f(u.z), scale[c4 + 2], shift[c4 + 2]) + xv.z, 0.f);
    o.w = fmaxf(fmaf(bf2f(u.w), scale[c4 + 3], shift[c4 + 3]) + xv.w, 0.f);
    ((float4*)out)[idx] = o;
}

// ---------------- launch ----------------

extern "C" void kernel_launch(void* const* d_in, const int* in_sizes, int n_in,
                              void* d_out, int out_size, void* d_ws, size_t ws_size,
                              hipStream_t stream) {
    const float* x  = (const float*)d_in[0];
    const int*   es = (const int*)d_in[1];
    const float* W1 = (const float*)d_in[2];
    const float* g1 = (const float*)d_in[3];
    const float* b1 = (const float*)d_in[4];
    const float* W2 = (const float*)d_in[5];
    const float* g2 = (const float*)d_in[6];
    const float* b2 = (const float*)d_in[7];
    float* out = (float*)d_out;

    const int E  = in_sizes[1] / 2;
    const int IC = in_sizes[3];   // 512
    const int C  = in_sizes[7];   // 256
    const int N  = in_sizes[0] / C;
    const int MTILES = (N + 127) / 128;   // 79
    const int CHUNKS2 = 512;

    const int* row = es;
    const int* col = es + E;

    // ---- workspace layout (zeroed region first: single memset) ----
    char* w = (char*)d_ws;
    size_t off = 0;
    auto alloc = [&](size_t bytes) -> void* {
        void* p = w + off;
        off = (off + bytes + 255) & ~(size_t)255;
        return p;
    };
    int*   cnt     = (int*)alloc((size_t)N * 4);
    int*   ticket1 = (int*)alloc(4);
    int*   ticket2 = (int*)alloc(4);
    size_t zero_bytes = off;              // cnt + tickets
    float* dis     = (float*)alloc((size_t)N * 4);
    int*   rowptr  = (int*)alloc((size_t)(N + 1) * 4);
    int*   cursor  = (int*)alloc((size_t)N * 4);
    int2*  adjw    = (int2*)alloc((size_t)E * 8);
    float* psum1   = (float*)alloc((size_t)IC * MTILES * 4);
    float* psumsq1 = (float*)alloc((size_t)IC * MTILES * 4);
    float* psum2   = (float*)alloc((size_t)C * CHUNKS2 * 4);
    float* psumsq2 = (float*)alloc((size_t)C * CHUNKS2 * 4);
    float* scale1  = (float*)alloc((size_t)IC * 4);
    float* shift1  = (float*)alloc((size_t)IC * 4);
    float* scale2  = (float*)alloc((size_t)C * 4);
    float* shift2  = (float*)alloc((size_t)C * 4);
    ushort* xbf    = (ushort*)alloc((size_t)N * C * 2);
    ushort* W1bf   = (ushort*)alloc((size_t)IC * C * 2);
    ushort* W2bf   = (ushort*)alloc((size_t)IC * C * 2);
    ushort* g1x    = (ushort*)alloc((size_t)N * C * 2);
    ushort* h1raw  = (ushort*)alloc((size_t)N * IC * 2);  // GEMM1 out, bf16 (pre-BN)
    ushort* xl2bf  = (ushort*)alloc((size_t)N * C * 2);
    ushort* h2     = (ushort*)alloc((size_t)N * C * 2);   // gather2 out, bf16

    hipMemsetAsync(cnt, 0, zero_bytes, stream);

    // ---- prep: degree count + bf16 casts ----
    {
        int n4x = N * C / 4, n4w = IC * C / 4;
        int tot = E + n4x + 2 * n4w;
        prep_kernel<<<(tot + 255) / 256, 256, 0, stream>>>(
            col, cnt, x, W1, W2, xbf, W1bf, W2bf, E, n4x, n4w);
    }
    scan_dis_kernel<<<1, 1024, 0, stream>>>(cnt, dis, rowptr, cursor, N);
    scatter_kernel<<<(E + 255) / 256, 256, 0, stream>>>(row, col, dis, cursor, adjw, E);

    // ---- layer 1: g1x = A_norm(x); h1raw = g1x @ W1^T (bf16 + stats1,
    //      last block finalizes scale1/shift1) ----
    gather_bf_kernel<<<N, 256, 0, stream>>>(xbf, rowptr, adjw, dis, g1x);
    {
        dim3 grid(IC / 128, MTILES);
        gemm_mfma_kernel<true, false><<<grid, 256, 0, stream>>>(
            g1x, W1bf, h1raw, psum1, psumsq1, nullptr, nullptr,
            g1, b1, scale1, shift1, ticket1, MTILES, N, IC, C);
    }

    // ---- layer 2: xl2 = relu(bn1(h1raw)) @ W2^T (BN fused into A staging,
    //      direct scale1/shift1 read — R3-proven) ----
    {
        dim3 grid(C / 128, MTILES);
        gemm_mfma_kernel<false, true><<<grid, 256, 0, stream>>>(
            h1raw, W2bf, xl2bf, nullptr, nullptr, scale1, shift1,
            nullptr, nullptr, nullptr, nullptr, nullptr, 0, N, C, IC);
    }
    gather_bf_kernel<<<N, 256, 0, stream>>>(xl2bf, rowptr, adjw, dis, h2);
    {
        int rpc = (N + CHUNKS2 - 1) / CHUNKS2;
        bn_partial_kernel<<<CHUNKS2, 256, 0, stream>>>(
            h2, psum2, psumsq2, g2, b2, scale2, shift2, ticket2, N, C, rpc, CHUNKS2);
    }

    // ---- epilogue: relu(bn2(h2) + x), saturating grid ----
    {
        int total4 = (N * C) / 4;
        final_kernel<<<(total4 + 255) / 256, 256, 0, stream>>>(h2, x, scale2, shift2, out, total4, C / 4);
    }
}

// Round 7
// 194.984 us; speedup vs baseline: 2.9351x; 2.9351x over previous
//
#include <hip/hip_runtime.h>

#define BN_EPS 1e-5f

typedef __attribute__((ext_vector_type(8))) short short8;
typedef __attribute__((ext_vector_type(8))) unsigned short ushort8v;
typedef __attribute__((ext_vector_type(4))) float floatx4;

#define GLL(gp, lp)                                                            \
    __builtin_amdgcn_global_load_lds(                                          \
        (const __attribute__((address_space(1))) void*)(gp),                   \
        (__attribute__((address_space(3))) void*)(lp), 16, 0, 0)

__device__ inline unsigned short f2bf(float f) {
    unsigned int u = __float_as_uint(f);
    unsigned int r = (u + 0x7FFF + ((u >> 16) & 1)) >> 16;  // RNE
    return (unsigned short)r;
}

__device__ inline float bf2f(unsigned short u) {
    return __uint_as_float(((unsigned int)u) << 16);
}

// ---------------- prep: count in-degree + fp32->bf16 casts (merged) --------

__global__ void prep_kernel(const int* __restrict__ col, int* __restrict__ cnt,
                            const float* __restrict__ x, const float* __restrict__ W1,
                            const float* __restrict__ W2, ushort* __restrict__ xbf,
                            ushort* __restrict__ W1bf, ushort* __restrict__ W2bf,
                            int E, int n4x, int n4w) {
    int i = blockIdx.x * blockDim.x + threadIdx.x;
    if (i < E) {
        atomicAdd(&cnt[col[i]], 1);
        return;
    }
    int j = i - E;
    const float* src;
    ushort* dst;
    if (j < n4x) { src = x; dst = xbf; }
    else if (j < n4x + n4w) { src = W1; dst = W1bf; j -= n4x; }
    else if (j < n4x + 2 * n4w) { src = W2; dst = W2bf; j -= n4x + n4w; }
    else return;
    float4 v = ((const float4*)src)[j];
    ushort4 o;
    o.x = f2bf(v.x); o.y = f2bf(v.y); o.z = f2bf(v.z); o.w = f2bf(v.w);
    ((ushort4*)dst)[j] = o;
}

// single-block scan over N counts -> rowptr/cursor; also computes dis.
__global__ __launch_bounds__(1024) void scan_dis_kernel(
    const int* __restrict__ cnt, float* __restrict__ dis,
    int* __restrict__ rowptr, int* __restrict__ cursor, int N) {
    __shared__ int sums[1024];
    int t = threadIdx.x;
    int per = (N + 1023) / 1024;
    int start = t * per;
    int local = 0;
    for (int i = 0; i < per; i++) {
        int idx = start + i;
        if (idx < N) {
            int cv = cnt[idx];
            local += cv;
            dis[idx] = rsqrtf((float)(cv + 1));   // +1 self loop
        }
    }
    sums[t] = local;
    __syncthreads();
    for (int off = 1; off < 1024; off <<= 1) {
        int v = (t >= off) ? sums[t - off] : 0;
        __syncthreads();
        sums[t] += v;
        __syncthreads();
    }
    int run = (t == 0) ? 0 : sums[t - 1];
    for (int i = 0; i < per; i++) {
        int idx = start + i;
        if (idx < N) {
            rowptr[idx] = run;
            cursor[idx] = run;
            run += cnt[idx];
        }
    }
    if (t == 0) rowptr[N] = sums[1023];
}

// scatter: build CSR adjacency with pre-baked dis[row].
__global__ void scatter_kernel(const int* __restrict__ row, const int* __restrict__ col,
                               const float* __restrict__ dis,
                               int* __restrict__ cursor, int2* __restrict__ adjw, int E) {
    int e = blockIdx.x * blockDim.x + threadIdx.x;
    if (e < E) {
        int r = row[e];
        int pos = atomicAdd(&cursor[col[e]], 1);
        adjw[pos] = make_int2(r, __float_as_int(dis[r]));
    }
}

// ---------------- bf16 gather, C=256 channels, one BLOCK per node ----------
// R3-PROVEN block structure (R4/R5/R6 lessons: do NOT restructure the grid or
// add cross-block sync). One change vs R3: the up-to-64 adjacency entries are
// preloaded in ONE coalesced wave load (adjw[e0+lane]) and fetched per-edge
// via __shfl, removing the adjw load from the per-edge dependent chain.

__global__ __launch_bounds__(256) void gather_bf_kernel(
    const ushort* __restrict__ xl, const int* __restrict__ rowptr,
    const int2* __restrict__ adjw, const float* __restrict__ dis,
    ushort* __restrict__ h) {
    int v = blockIdx.x;
    int wave = threadIdx.x >> 6;
    int lane = threadIdx.x & 63;
    float dv = dis[v];

    int e0 = rowptr[v], e1 = rowptr[v + 1];
    int cnt = e1 - e0;
    // coalesced adjacency preload into lane registers (512B per wave)
    int pidx = e0 + lane;
    if (pidx >= e1) pidx = (e1 > 0) ? (e1 - 1) : 0;
    int2 am = adjw[pidx];
    int aidx = am.x;
    float awgt = __int_as_float(am.y) * dv;   // premultiplied weight

    int cnt64 = cnt < 64 ? cnt : 64;
    float a0 = 0.f, a1 = 0.f, a2 = 0.f, a3 = 0.f;
    float b0 = 0.f, b1 = 0.f, b2 = 0.f, b3 = 0.f;
    int j = wave;
    for (; j + 4 < cnt64; j += 8) {
        int ra = __shfl(aidx, j, 64);
        float wa = __shfl(awgt, j, 64);
        int rb = __shfl(aidx, j + 4, 64);
        float wb = __shfl(awgt, j + 4, 64);
        ushort4 ua = ((const ushort4*)xl)[(size_t)ra * 64 + lane];
        ushort4 ub = ((const ushort4*)xl)[(size_t)rb * 64 + lane];
        a0 = fmaf(bf2f(ua.x), wa, a0);
        a1 = fmaf(bf2f(ua.y), wa, a1);
        a2 = fmaf(bf2f(ua.z), wa, a2);
        a3 = fmaf(bf2f(ua.w), wa, a3);
        b0 = fmaf(bf2f(ub.x), wb, b0);
        b1 = fmaf(bf2f(ub.y), wb, b1);
        b2 = fmaf(bf2f(ub.z), wb, b2);
        b3 = fmaf(bf2f(ub.w), wb, b3);
    }
    if (j < cnt64) {
        int ra = __shfl(aidx, j, 64);
        float wa = __shfl(awgt, j, 64);
        ushort4 ua = ((const ushort4*)xl)[(size_t)ra * 64 + lane];
        a0 = fmaf(bf2f(ua.x), wa, a0);
        a1 = fmaf(bf2f(ua.y), wa, a1);
        a2 = fmaf(bf2f(ua.z), wa, a2);
        a3 = fmaf(bf2f(ua.w), wa, a3);
    }
    // rare tail: degree > 64, direct R3-style loads
    for (int e = e0 + 64 + wave; e < e1; e += 4) {
        int2 ea = adjw[e];
        float wa = __int_as_float(ea.y) * dv;
        ushort4 ua = ((const ushort4*)xl)[(size_t)ea.x * 64 + lane];
        a0 = fmaf(bf2f(ua.x), wa, a0);
        a1 = fmaf(bf2f(ua.y), wa, a1);
        a2 = fmaf(bf2f(ua.z), wa, a2);
        a3 = fmaf(bf2f(ua.w), wa, a3);
    }
    a0 += b0; a1 += b1; a2 += b2; a3 += b3;

    __shared__ float4 red[4][64];
    red[wave][lane] = make_float4(a0, a1, a2, a3);
    __syncthreads();
    if (wave == 0) {
        float4 s = red[0][lane];
        float4 b = red[1][lane];
        float4 c = red[2][lane];
        float4 d = red[3][lane];
        s.x += b.x + c.x + d.x;
        s.y += b.y + c.y + d.y;
        s.z += b.z + c.z + d.z;
        s.w += b.w + c.w + d.w;
        ushort4 u = ((const ushort4*)xl)[(size_t)v * 64 + lane];
        float w2 = dv * dv;
        s.x = fmaf(bf2f(u.x), w2, s.x);
        s.y = fmaf(bf2f(u.y), w2, s.y);
        s.z = fmaf(bf2f(u.z), w2, s.z);
        s.w = fmaf(bf2f(u.w), w2, s.w);
        ushort4 o;
        o.x = f2bf(s.x); o.y = f2bf(s.y); o.z = f2bf(s.z); o.w = f2bf(s.w);
        ((ushort4*)h)[(size_t)v * 64 + lane] = o;
    }
}

// ---------------- MFMA GEMM: C[M,N] = A[M,K] @ B[N,K]^T (bf16 in/out) ------
// STATS: epilogue emits per-column partial sum/sumsq into psum[col][chunk].
// BN_A:  A-tile is reg-staged global->reg, BN(scale,shift)+ReLU applied, then
//        ds_write to LDS (replaces the standalone bn_apply pass).

template <bool STATS, bool BN_A>
__global__ __launch_bounds__(256) void gemm_mfma_kernel(
    const ushort* __restrict__ A, const ushort* __restrict__ B,
    ushort* __restrict__ Cout, float* __restrict__ psum, float* __restrict__ psumsq,
    const float* __restrict__ bnScale, const float* __restrict__ bnShift,
    int chunks, int M, int N, int K) {
    __shared__ ushort As[128 * 32];
    __shared__ ushort Bs[128 * 32];
    int tid = threadIdx.x;
    int wave = tid >> 6;
    int lane = tid & 63;
    int quad = lane >> 4;
    int l15 = lane & 15;
    int m0 = blockIdx.y * 128;
    int n0 = blockIdx.x * 128;

    int srow = lane >> 2;
    int skoff = (lane & 3) * 8;

    floatx4 acc[4][4];
#pragma unroll
    for (int i = 0; i < 4; i++)
#pragma unroll
        for (int j = 0; j < 4; j++) acc[i][j] = (floatx4){0.f, 0.f, 0.f, 0.f};

    int wm = (wave & 1) * 64;
    int wn = (wave >> 1) * 64;

    for (int k0 = 0; k0 < K; k0 += 32) {
#pragma unroll
        for (int cc = 0; cc < 2; cc++) {
            int c = wave * 2 + cc;
            int brow = n0 + c * 16 + srow;
            const ushort* gb = B + (size_t)brow * K + k0 + skoff;
            GLL(gb, (char*)Bs + c * 1024);
            if (!BN_A) {
                int arow = min(m0 + c * 16 + srow, M - 1);
                const ushort* ga = A + (size_t)arow * K + k0 + skoff;
                GLL(ga, (char*)As + c * 1024);
            }
        }
        if (BN_A) {
            const float* scp = bnScale + k0 + skoff;
            const float* shp = bnShift + k0 + skoff;
            float4 sa = *(const float4*)scp;
            float4 sb = *(const float4*)(scp + 4);
            float4 ha = *(const float4*)shp;
            float4 hb = *(const float4*)(shp + 4);
            float scv[8] = {sa.x, sa.y, sa.z, sa.w, sb.x, sb.y, sb.z, sb.w};
            float shv[8] = {ha.x, ha.y, ha.z, ha.w, hb.x, hb.y, hb.z, hb.w};
#pragma unroll
            for (int cc = 0; cc < 2; cc++) {
                int c = wave * 2 + cc;
                int arow = min(m0 + c * 16 + srow, M - 1);
                ushort8v araw = *(const ushort8v*)(A + (size_t)arow * K + k0 + skoff);
                ushort8v t;
#pragma unroll
                for (int j = 0; j < 8; j++) {
                    float f = fmaxf(fmaf(bf2f(araw[j]), scv[j], shv[j]), 0.f);
                    t[j] = f2bf(f);
                }
                // tail barrier of previous iter guarantees buffer is free
                *(ushort8v*)((char*)As + c * 1024 + (size_t)lane * 16) = t;
            }
        }
        __syncthreads();

        short8 af[4], bfr[4];
#pragma unroll
        for (int i = 0; i < 4; i++) {
            int r = wm + i * 16 + l15;
            af[i] = *(const short8*)(As + r * 32 + quad * 8);
        }
#pragma unroll
        for (int j = 0; j < 4; j++) {
            int r = wn + j * 16 + l15;
            bfr[j] = *(const short8*)(Bs + r * 32 + quad * 8);
        }
#pragma unroll
        for (int i = 0; i < 4; i++)
#pragma unroll
            for (int j = 0; j < 4; j++)
                acc[i][j] = __builtin_amdgcn_mfma_f32_16x16x32_bf16(af[i], bfr[j], acc[i][j], 0, 0, 0);
        __syncthreads();
    }

#pragma unroll
    for (int i = 0; i < 4; i++) {
#pragma unroll
        for (int r = 0; r < 4; r++) {
            int row = m0 + wm + i * 16 + quad * 4 + r;
            if (row < M) {
                ushort* cp = Cout + (size_t)row * N + n0 + wn + l15;
#pragma unroll
                for (int j = 0; j < 4; j++) cp[j * 16] = f2bf(acc[i][j][r]);
            }
        }
    }

    if (STATS) {
        float s[4] = {0.f, 0.f, 0.f, 0.f};
        float q[4] = {0.f, 0.f, 0.f, 0.f};
#pragma unroll
        for (int i = 0; i < 4; i++) {
#pragma unroll
            for (int r = 0; r < 4; r++) {
                if (m0 + wm + i * 16 + quad * 4 + r < M) {
#pragma unroll
                    for (int j = 0; j < 4; j++) {
                        float v = acc[i][j][r];
                        s[j] += v;
                        q[j] += v * v;
                    }
                }
            }
        }
#pragma unroll
        for (int j = 0; j < 4; j++) {
            s[j] += __shfl_xor(s[j], 16, 64);
            s[j] += __shfl_xor(s[j], 32, 64);
            q[j] += __shfl_xor(q[j], 16, 64);
            q[j] += __shfl_xor(q[j], 32, 64);
        }
        __shared__ float sArr[4][64];
        __shared__ float qArr[4][64];
        if (quad == 0) {
#pragma unroll
            for (int j = 0; j < 4; j++) {
                sArr[wave][j * 16 + l15] = s[j];
                qArr[wave][j * 16 + l15] = q[j];
            }
        }
        __syncthreads();
        if (tid < 128) {
            int half = tid >> 6;
            int cc = tid & 63;
            float ss = sArr[half * 2][cc] + sArr[half * 2 + 1][cc];
            float qq = qArr[half * 2][cc] + qArr[half * 2 + 1][cc];
            int colI = n0 + half * 64 + cc;
            psum[(size_t)colI * chunks + blockIdx.y] = ss;
            psumsq[(size_t)colI * chunks + blockIdx.y] = qq;
        }
    }
}

// ---------------- BN2 partial stats on bf16 h (channel-major [C][chunks]) ---
// Non-atomic: each block owns its chunk column. Proven (~4us). Cross-block
// finalize stays a SEPARATE dispatch — fusion attempts cost 230-270us
// (atomics R1/R2, coop R4/R5, ticket+threadfence R6).

__global__ __launch_bounds__(256) void bn_partial_kernel(
    const ushort* __restrict__ h, float* __restrict__ psum, float* __restrict__ psumsq,
    int N, int IC, int rows_per_chunk, int chunks) {
    int groups = IC >> 2;          // 64 for C=256
    int rpi = 256 / groups;        // 4
    int t = threadIdx.x;
    int g = t & (groups - 1);
    int ro = t / groups;
    int r0 = blockIdx.x * rows_per_chunk;
    int r1 = min(r0 + rows_per_chunk, N);

    float4 s = make_float4(0.f, 0.f, 0.f, 0.f);
    float4 q = make_float4(0.f, 0.f, 0.f, 0.f);
    for (int r = r0 + ro; r < r1; r += rpi) {
        ushort4 u = *(const ushort4*)(h + (size_t)r * IC + g * 4);
        float vx = bf2f(u.x), vy = bf2f(u.y), vz = bf2f(u.z), vw = bf2f(u.w);
        s.x += vx; s.y += vy; s.z += vz; s.w += vw;
        q.x += vx * vx; q.y += vy * vy; q.z += vz * vz; q.w += vw * vw;
    }

    __shared__ float4 redS[256];
    __shared__ float4 redQ[256];
    redS[t] = s;
    redQ[t] = q;
    __syncthreads();
    if (ro == 0) {
        for (int i = 1; i < rpi; i++) {
            float4 o = redS[t + i * groups];
            s.x += o.x; s.y += o.y; s.z += o.z; s.w += o.w;
            float4 p = redQ[t + i * groups];
            q.x += p.x; q.y += p.y; q.z += p.z; q.w += p.w;
        }
        int k = blockIdx.x;
        psum[(size_t)(4 * g + 0) * chunks + k] = s.x;
        psum[(size_t)(4 * g + 1) * chunks + k] = s.y;
        psum[(size_t)(4 * g + 2) * chunks + k] = s.z;
        psum[(size_t)(4 * g + 3) * chunks + k] = s.w;
        psumsq[(size_t)(4 * g + 0) * chunks + k] = q.x;
        psumsq[(size_t)(4 * g + 1) * chunks + k] = q.y;
        psumsq[(size_t)(4 * g + 2) * chunks + k] = q.z;
        psumsq[(size_t)(4 * g + 3) * chunks + k] = q.w;
    }
}

// one wave per channel; coalesced lane-parallel reduce -> scale/shift.
__global__ __launch_bounds__(256) void bn_reduce_kernel(
    const float* __restrict__ psum, const float* __restrict__ psumsq,
    const float* __restrict__ gamma, const float* __restrict__ beta,
    float* __restrict__ scale, float* __restrict__ shift,
    int N, int chunks) {
    int wave = threadIdx.x >> 6;
    int lane = threadIdx.x & 63;
    int c = blockIdx.x * 4 + wave;
    float s = 0.f, q = 0.f;
    for (int k = lane; k < chunks; k += 64) {
        s += psum[(size_t)c * chunks + k];
        q += psumsq[(size_t)c * chunks + k];
    }
#pragma unroll
    for (int off = 32; off > 0; off >>= 1) {
        s += __shfl_down(s, off, 64);
        q += __shfl_down(q, off, 64);
    }
    if (lane == 0) {
        float invN = 1.0f / (float)N;
        float mean = s * invN;
        float var = q * invN - mean * mean;
        float sc = gamma[c] * rsqrtf(var + BN_EPS);
        scale[c] = sc;
        shift[c] = beta[c] - mean * sc;
    }
}

// ---------------- final: out = relu(bn2(h2) + x), large grid (bf16 h2) ------

__global__ void final_kernel(const ushort* __restrict__ h2, const float* __restrict__ x,
                             const float* __restrict__ scale, const float* __restrict__ shift,
                             float* __restrict__ out, int total4, int C4) {
    int idx = blockIdx.x * blockDim.x + threadIdx.x;
    if (idx >= total4) return;
    int c4 = (idx & (C4 - 1)) * 4;
    ushort4 u = ((const ushort4*)h2)[idx];
    float4 xv = ((const float4*)x)[idx];
    float4 o;
    o.x = fmaxf(fmaf(bf2f(u.x), scale[c4 + 0], shift[c4 + 0]) + xv.x, 0.f);
    o.y = fmaxf(fmaf(bf2f(u.y), scale[c4 + 1], shift[c4 + 1]) + xv.y, 0.f);
    o.z = fmaxf(fmaf(bf2f(u.z), scale[c4 + 2], shift[c4 + 2]) + xv.z, 0.f);
    o.w = fmaxf(fmaf(bf2f(u.w), scale[c4 + 3], shift[c4 + 3]) + xv.w, 0.f);
    ((float4*)out)[idx] = o;
}

// ---------------- launch ----------------

extern "C" void kernel_launch(void* const* d_in, const int* in_sizes, int n_in,
                              void* d_out, int out_size, void* d_ws, size_t ws_size,
                              hipStream_t stream) {
    const float* x  = (const float*)d_in[0];
    const int*   es = (const int*)d_in[1];
    const float* W1 = (const float*)d_in[2];
    const float* g1 = (const float*)d_in[3];
    const float* b1 = (const float*)d_in[4];
    const float* W2 = (const float*)d_in[5];
    const float* g2 = (const float*)d_in[6];
    const float* b2 = (const float*)d_in[7];
    float* out = (float*)d_out;

    const int E  = in_sizes[1] / 2;
    const int IC = in_sizes[3];   // 512
    const int C  = in_sizes[7];   // 256
    const int N  = in_sizes[0] / C;
    const int MTILES = (N + 127) / 128;   // 79
    const int CHUNKS2 = 512;

    const int* row = es;
    const int* col = es + E;

    // ---- workspace layout (cnt first: single memset) ----
    char* w = (char*)d_ws;
    size_t off = 0;
    auto alloc = [&](size_t bytes) -> void* {
        void* p = w + off;
        off = (off + bytes + 255) & ~(size_t)255;
        return p;
    };
    int*   cnt     = (int*)alloc((size_t)N * 4);
    float* dis     = (float*)alloc((size_t)N * 4);
    int*   rowptr  = (int*)alloc((size_t)(N + 1) * 4);
    int*   cursor  = (int*)alloc((size_t)N * 4);
    int2*  adjw    = (int2*)alloc((size_t)E * 8);
    float* psum1   = (float*)alloc((size_t)IC * MTILES * 4);
    float* psumsq1 = (float*)alloc((size_t)IC * MTILES * 4);
    float* psum2   = (float*)alloc((size_t)C * CHUNKS2 * 4);
    float* psumsq2 = (float*)alloc((size_t)C * CHUNKS2 * 4);
    float* scale1  = (float*)alloc((size_t)IC * 4);
    float* shift1  = (float*)alloc((size_t)IC * 4);
    float* scale2  = (float*)alloc((size_t)C * 4);
    float* shift2  = (float*)alloc((size_t)C * 4);
    ushort* xbf    = (ushort*)alloc((size_t)N * C * 2);
    ushort* W1bf   = (ushort*)alloc((size_t)IC * C * 2);
    ushort* W2bf   = (ushort*)alloc((size_t)IC * C * 2);
    ushort* g1x    = (ushort*)alloc((size_t)N * C * 2);
    ushort* h1raw  = (ushort*)alloc((size_t)N * IC * 2);  // GEMM1 out, bf16 (pre-BN)
    ushort* xl2bf  = (ushort*)alloc((size_t)N * C * 2);
    ushort* h2     = (ushort*)alloc((size_t)N * C * 2);   // gather2 out, bf16

    hipMemsetAsync(cnt, 0, (size_t)N * 4, stream);

    // ---- prep: degree count + bf16 casts ----
    {
        int n4x = N * C / 4, n4w = IC * C / 4;
        int tot = E + n4x + 2 * n4w;
        prep_kernel<<<(tot + 255) / 256, 256, 0, stream>>>(
            col, cnt, x, W1, W2, xbf, W1bf, W2bf, E, n4x, n4w);
    }
    scan_dis_kernel<<<1, 1024, 0, stream>>>(cnt, dis, rowptr, cursor, N);
    scatter_kernel<<<(E + 255) / 256, 256, 0, stream>>>(row, col, dis, cursor, adjw, E);

    // ---- layer 1: g1x = A_norm(x); h1raw = g1x @ W1^T (bf16 + stats1) ----
    gather_bf_kernel<<<N, 256, 0, stream>>>(xbf, rowptr, adjw, dis, g1x);
    {
        dim3 grid(IC / 128, MTILES);
        gemm_mfma_kernel<true, false><<<grid, 256, 0, stream>>>(
            g1x, W1bf, h1raw, psum1, psumsq1, nullptr, nullptr, MTILES, N, IC, C);
    }
    bn_reduce_kernel<<<IC / 4, 256, 0, stream>>>(psum1, psumsq1, g1, b1, scale1, shift1, N, MTILES);

    // ---- layer 2: xl2 = relu(bn1(h1raw)) @ W2^T (BN fused into A staging);
    //      h2 = A_norm(xl2) ----
    {
        dim3 grid(C / 128, MTILES);
        gemm_mfma_kernel<false, true><<<grid, 256, 0, stream>>>(
            h1raw, W2bf, xl2bf, scale1, shift1, scale1, shift1, 0, N, C, IC);
    }
    gather_bf_kernel<<<N, 256, 0, stream>>>(xl2bf, rowptr, adjw, dis, h2);
    {
        int rpc = (N + CHUNKS2 - 1) / CHUNKS2;
        bn_partial_kernel<<<CHUNKS2, 256, 0, stream>>>(h2, psum2, psumsq2, N, C, rpc, CHUNKS2);
    }
    bn_reduce_kernel<<<C / 4, 256, 0, stream>>>(psum2, psumsq2, g2, b2, scale2, shift2, N, CHUNKS2);

    // ---- epilogue: relu(bn2(h2) + x), saturating grid ----
    {
        int total4 = (N * C) / 4;
        final_kernel<<<(total4 + 255) / 256, 256, 0, stream>>>(h2, x, scale2, shift2, out, total4, C / 4);
    }
}